// Round 7
// baseline (225.756 us; speedup 1.0000x reference)
//
#include <hip/hip_runtime.h>
#include <hip/hip_bf16.h>
#include <stdint.h>

#define N_NODES 50000
#define N_EDGES 800000
#define IN_C 512
#define HID_C 256
#define TOT_E (N_EDGES + N_NODES)   // edges + self loops

typedef __attribute__((ext_vector_type(8))) short bf16x8;
typedef __attribute__((ext_vector_type(4))) float f32x4;
typedef __attribute__((address_space(3))) uint32_t lds_u32_t;
typedef __attribute__((address_space(1))) const uint32_t g_u32_t;

__device__ __forceinline__ void g2l16(const void* g, void* l) {
    __builtin_amdgcn_global_load_lds((g_u32_t*)g, (lds_u32_t*)l, 16, 0, 0);
}

__device__ __forceinline__ unsigned short f2bf(float f) {
    uint32_t u = __float_as_uint(f);
    uint32_t r = (u + 0x7fff + ((u >> 16) & 1)) >> 16;
    return (unsigned short)r;
}

// ---------------- init: counts = 0 ----------------

__global__ void init0_kernel(int* counts, int n) {
    int i = blockIdx.x * blockDim.x + threadIdx.x;
    if (i < n) counts[i] = 0;
}

// ---------------- prep: W1 transpose+convert, edge-degree count ----------------
// blocks [0,256): transw (block = output col n)
// blocks [256,...): count edge dst degrees, 4 edges/thread

#define TRANSW_BLOCKS 256
#define COUNT_BLOCKS ((N_EDGES + 1023) / 1024)   // 782
#define PREP_BLOCKS (TRANSW_BLOCKS + COUNT_BLOCKS)

__global__ __launch_bounds__(256) void prep_kernel(int* __restrict__ counts,
                                                   const float* __restrict__ W1,
                                                   unsigned short* __restrict__ Wt,
                                                   const int* __restrict__ e_dst) {
    const int b = blockIdx.x;
    const int t = threadIdx.x;
    if (b < TRANSW_BLOCKS) {
        const int n = b;   // 0..255
        for (int k = t; k < IN_C; k += 256)
            Wt[n * IN_C + k] = f2bf(W1[k * HID_C + n]);
    } else {
        const int i0 = ((b - TRANSW_BLOCKS) * 256 + t) * 4;
        if (i0 + 4 <= N_EDGES) {
            const int4 d4 = *(const int4*)&e_dst[i0];
            atomicAdd(&counts[d4.x], 1);
            atomicAdd(&counts[d4.y], 1);
            atomicAdd(&counts[d4.z], 1);
            atomicAdd(&counts[d4.w], 1);
        } else {
            for (int i = i0; i < N_EDGES; ++i) atomicAdd(&counts[e_dst[i]], 1);
        }
    }
}

// ---------------- hierarchical scan over deg = counts+1; emits dinv ----------------

__global__ __launch_bounds__(256) void scan1_kernel(const int* __restrict__ counts,
                                                    int* __restrict__ incl,
                                                    int* __restrict__ bsum,
                                                    float* __restrict__ dinv, int n) {
    __shared__ int buf[256];
    const int i = blockIdx.x * 256 + threadIdx.x;
    const int v = (i < n) ? counts[i] + 1 : 0;    // +1 self loop
    if (i < n) dinv[i] = rsqrtf((float)v);
    buf[threadIdx.x] = v;
    __syncthreads();
    #pragma unroll
    for (int off = 1; off < 256; off <<= 1) {
        const int t2 = (threadIdx.x >= off) ? buf[threadIdx.x - off] : 0;
        __syncthreads();
        buf[threadIdx.x] += t2;
        __syncthreads();
    }
    if (i < n) incl[i] = buf[threadIdx.x];
    if (threadIdx.x == 255) bsum[blockIdx.x] = buf[255];
}

// scan2+scan3 fused: each block reduces bsum[0..bid) itself (196 values, cheap)
__global__ __launch_bounds__(256) void scan23_kernel(const int* __restrict__ incl,
                                                     const int* __restrict__ counts,
                                                     const int* __restrict__ bsum,
                                                     int* __restrict__ offs,
                                                     int* __restrict__ cursor,
                                                     int n, int nb) {
    __shared__ int red[4];
    const int t = threadIdx.x;
    int v = (t < nb && t < blockIdx.x) ? bsum[t] : 0;
    #pragma unroll
    for (int o = 32; o > 0; o >>= 1) v += __shfl_down(v, o, 64);
    const int wid = t >> 6, lane = t & 63;
    if (lane == 0) red[wid] = v;
    __syncthreads();
    const int prefix = red[0] + red[1] + red[2] + red[3];
    const int i = blockIdx.x * 256 + t;
    if (i >= n) return;
    const int e = incl[i] + prefix;
    offs[i + 1] = e;
    cursor[i] = e - (counts[i] + 1);
    if (i == 0) offs[0] = 0;
}

// ---------------- CSR fill: packed {src, norm} uint2, 4 slots/thread ----------------

__global__ __launch_bounds__(256) void fill_kernel(const int* __restrict__ src,
                                                   const int* __restrict__ dst,
                                                   const float* __restrict__ dinv,
                                                   int* cursor,
                                                   uint2* __restrict__ csr_pack) {
    const int i0 = (blockIdx.x * 256 + threadIdx.x) * 4;
    if (i0 >= TOT_E) return;
    int s[4], d[4];
    if (i0 + 4 <= N_EDGES) {
        const int4 s4 = *(const int4*)&src[i0];
        const int4 d4 = *(const int4*)&dst[i0];
        s[0] = s4.x; s[1] = s4.y; s[2] = s4.z; s[3] = s4.w;
        d[0] = d4.x; d[1] = d4.y; d[2] = d4.z; d[3] = d4.w;
    } else {
        #pragma unroll
        for (int j = 0; j < 4; ++j) {
            const int i = i0 + j;
            if (i < N_EDGES)    { s[j] = src[i]; d[j] = dst[i]; }
            else if (i < TOT_E) { s[j] = d[j] = i - N_EDGES; }
            else                { s[j] = d[j] = -1; }
        }
    }
    float ds[4], dd[4];
    #pragma unroll
    for (int j = 0; j < 4; ++j) {
        if (s[j] >= 0) { ds[j] = dinv[s[j]]; dd[j] = dinv[d[j]]; }
    }
    #pragma unroll
    for (int j = 0; j < 4; ++j) {
        if (s[j] >= 0) {
            const int p = atomicAdd(&cursor[d[j]], 1);
            csr_pack[p] = make_uint2((uint32_t)s[j], __float_as_uint(ds[j] * dd[j]));
        }
    }
}

// ---------------- GEMM: h = bf16(x) @ W1, m97 structure, reg-staged f32 A ----------------
// tile 128x128x64, 256 thr / 4 waves. A: f32 loaded to regs (issue-early),
// converted + ds_write after barrier (write-late). B: bf16 via global_load_lds.
// LDS tiles [row][64] bf16, 16B-slot XOR swizzle: slot = c ^ (row&7).

__global__ __launch_bounds__(256) void gemm_kernel(
    const float* __restrict__ A,            // [M, 512] f32
    const unsigned short* __restrict__ Bt,  // [256, 512] bf16 (W1^T)
    unsigned short* __restrict__ hB,        // [M, 256] bf16 out
    int M)
{
    __shared__ unsigned short As[128 * 64];   // 16 KB
    __shared__ unsigned short Bs[128 * 64];   // 16 KB
    const int t = threadIdx.x;
    const int m0 = (blockIdx.x >> 1) * 128;
    const int n0 = (blockIdx.x & 1) * 128;
    const int w = t >> 6, l = t & 63;
    const int wr = (w >> 1) * 64, wc = (w & 1) * 64;
    const int l15 = l & 15, l4 = l >> 4;

    f32x4 acc[4][4] = {};
    float4 av[8];

    const int ar = t >> 1;                 // A row 0..127
    const int ac0 = (t & 1) * 32;          // col half

    auto loadA = [&](int kt) {             // issue 8 float4 loads (in-flight during compute)
        int gr = m0 + ar; if (gr >= M) gr = M - 1;
        const float* p = &A[(size_t)gr * IN_C + kt * 64 + ac0];
        #pragma unroll
        for (int j = 0; j < 8; ++j) av[j] = ((const float4*)p)[j];
    };
    auto writeA = [&]() {                  // convert + swizzled ds_write_b128
        __attribute__((aligned(16))) unsigned short tmp[32];
        #pragma unroll
        for (int j = 0; j < 8; ++j) {
            tmp[4*j+0] = f2bf(av[j].x); tmp[4*j+1] = f2bf(av[j].y);
            tmp[4*j+2] = f2bf(av[j].z); tmp[4*j+3] = f2bf(av[j].w);
        }
        const int c0 = (t & 1) * 4;
        #pragma unroll
        for (int hh = 0; hh < 4; ++hh) {
            const int ck = (c0 + hh) ^ (ar & 7);
            *(uint4*)&As[ar * 64 + ck * 8] = *(const uint4*)&tmp[hh * 8];
        }
    };
    auto stageB = [&](int kt) {
        #pragma unroll
        for (int q = 0; q < 4; ++q) {
            const int idx = q * 256 + t;
            const int row = idx >> 3;
            const int ck  = (idx & 7) ^ (row & 7);
            g2l16(&Bt[(size_t)(n0 + row) * IN_C + kt * 64 + ck * 8], &Bs[idx * 8]);
        }
    };

    loadA(0); writeA(); stageB(0);
    for (int kt = 0; kt < 8; ++kt) {
        __syncthreads();                   // drains g2l16 (vmcnt0) + ds_write -> LDS ready
        if (kt < 7) loadA(kt + 1);         // issue next A loads; fly during compute
        #pragma unroll
        for (int kc = 0; kc < 2; ++kc) {
            bf16x8 a[4], b[4];
            #pragma unroll
            for (int mi = 0; mi < 4; ++mi) {
                const int r  = wr + mi * 16 + l15;
                const int ck = (kc * 4 + l4) ^ (r & 7);
                a[mi] = *(const bf16x8*)&As[r * 64 + ck * 8];
            }
            #pragma unroll
            for (int nj = 0; nj < 4; ++nj) {
                const int r  = wc + nj * 16 + l15;
                const int ck = (kc * 4 + l4) ^ (r & 7);
                b[nj] = *(const bf16x8*)&Bs[r * 64 + ck * 8];
            }
            #pragma unroll
            for (int mi = 0; mi < 4; ++mi)
                #pragma unroll
                for (int nj = 0; nj < 4; ++nj)
                    acc[mi][nj] = __builtin_amdgcn_mfma_f32_16x16x32_bf16(
                        a[mi], b[nj], acc[mi][nj], 0, 0, 0);
        }
        if (kt < 7) {
            __syncthreads();               // compute done -> safe to overwrite LDS
            writeA(); stageB(kt + 1);
        }
    }

    #pragma unroll
    for (int mi = 0; mi < 4; ++mi)
        #pragma unroll
        for (int nj = 0; nj < 4; ++nj)
            #pragma unroll
            for (int rr = 0; rr < 4; ++rr) {
                const int m = m0 + wr + mi * 16 + l4 * 4 + rr;
                const int n = n0 + wc + nj * 16 + l15;
                if (m < M) hB[(size_t)m * HID_C + n] = f2bf(acc[mi][nj][rr]);
            }
}

// ---------------- fused aggregation-1 + bias + ReLU + @W2 ----------------
// 32-lane group per node (2 nodes/wave): 8 feats/lane via uint4, 4-way gather ILP.

__device__ __forceinline__ void fma8(float* acc, uint4 r, float w) {
    acc[0] += __uint_as_float((r.x & 0xffffu) << 16) * w;
    acc[1] += __uint_as_float(r.x & 0xffff0000u) * w;
    acc[2] += __uint_as_float((r.y & 0xffffu) << 16) * w;
    acc[3] += __uint_as_float(r.y & 0xffff0000u) * w;
    acc[4] += __uint_as_float((r.z & 0xffffu) << 16) * w;
    acc[5] += __uint_as_float(r.z & 0xffff0000u) * w;
    acc[6] += __uint_as_float((r.w & 0xffffu) << 16) * w;
    acc[7] += __uint_as_float(r.w & 0xffff0000u) * w;
}

__global__ __launch_bounds__(256) void agg1_kernel(const unsigned short* __restrict__ h, // [N,256] bf16
                                                   const int* __restrict__ offs,
                                                   const uint2* __restrict__ csr_pack,
                                                   const float* __restrict__ b1,
                                                   const float* __restrict__ W2,  // [256,2]
                                                   float* __restrict__ h2) {      // [N,2]
    const int node = blockIdx.x * 8 + (threadIdx.x >> 5);
    const int g = threadIdx.x & 31;
    const int f0 = g << 3;
    const int s = offs[node], e = offs[node + 1];

    float acc[8] = {};

    for (int base = s; base < e; base += 32) {
        const int rem = e - base;
        const int cnt = rem < 32 ? rem : 32;
        int idx = 0; float nw = 0.f;
        if (g < cnt) {
            const uint2 pk = csr_pack[base + g];
            idx = (int)pk.x; nw = __uint_as_float(pk.y);
        }
        int i = 0;
        for (; i + 4 <= cnt; i += 4) {
            const int   i0 = __shfl(idx, i,     32); const float w0 = __shfl(nw, i,     32);
            const int   i1 = __shfl(idx, i + 1, 32); const float w1 = __shfl(nw, i + 1, 32);
            const int   i2 = __shfl(idx, i + 2, 32); const float w2 = __shfl(nw, i + 2, 32);
            const int   i3 = __shfl(idx, i + 3, 32); const float w3 = __shfl(nw, i + 3, 32);
            const uint4 r0 = *(const uint4*)&h[(size_t)i0 * HID_C + f0];
            const uint4 r1 = *(const uint4*)&h[(size_t)i1 * HID_C + f0];
            const uint4 r2 = *(const uint4*)&h[(size_t)i2 * HID_C + f0];
            const uint4 r3 = *(const uint4*)&h[(size_t)i3 * HID_C + f0];
            fma8(acc, r0, w0); fma8(acc, r1, w1); fma8(acc, r2, w2); fma8(acc, r3, w3);
        }
        for (; i < cnt; ++i) {
            const int   ii = __shfl(idx, i, 32);
            const float w  = __shfl(nw,  i, 32);
            const uint4 r  = *(const uint4*)&h[(size_t)ii * HID_C + f0];
            fma8(acc, r, w);
        }
    }

    const float4 ba = *(const float4*)&b1[f0];
    const float4 bb = *(const float4*)&b1[f0 + 4];
    float v[8];
    v[0] = fmaxf(acc[0] + ba.x, 0.f); v[1] = fmaxf(acc[1] + ba.y, 0.f);
    v[2] = fmaxf(acc[2] + ba.z, 0.f); v[3] = fmaxf(acc[3] + ba.w, 0.f);
    v[4] = fmaxf(acc[4] + bb.x, 0.f); v[5] = fmaxf(acc[5] + bb.y, 0.f);
    v[6] = fmaxf(acc[6] + bb.z, 0.f); v[7] = fmaxf(acc[7] + bb.w, 0.f);

    float c0 = 0.f, c1 = 0.f;
    #pragma unroll
    for (int q = 0; q < 4; ++q) {
        const float4 wv = *(const float4*)&W2[f0 * 2 + q * 4];  // rows f0+2q, f0+2q+1
        c0 += v[2*q] * wv.x + v[2*q+1] * wv.z;
        c1 += v[2*q] * wv.y + v[2*q+1] * wv.w;
    }
    #pragma unroll
    for (int o = 16; o > 0; o >>= 1) {
        c0 += __shfl_down(c0, o, 32);
        c1 += __shfl_down(c1, o, 32);
    }
    if (g == 0) *(float2*)&h2[node * 2] = make_float2(c0, c1);
}

// ---------------- aggregation-2 (+b2), 4-way ILP, packed csr ----------------

__global__ void agg2_kernel(const float* __restrict__ h2,
                            const int* __restrict__ offs,
                            const uint2* __restrict__ csr_pack,
                            const float* __restrict__ b2,
                            float* __restrict__ out, int n_nodes) {
    int n = blockIdx.x * blockDim.x + threadIdx.x;
    if (n >= n_nodes) return;
    const int s = offs[n], e = offs[n + 1];
    float a0 = b2[0], a1 = b2[1];
    int i = s;
    for (; i + 4 <= e; i += 4) {
        const uint2 k0 = csr_pack[i],     k1 = csr_pack[i + 1];
        const uint2 k2 = csr_pack[i + 2], k3 = csr_pack[i + 3];
        const float2 p0 = *(const float2*)&h2[k0.x * 2];
        const float2 p1 = *(const float2*)&h2[k1.x * 2];
        const float2 p2 = *(const float2*)&h2[k2.x * 2];
        const float2 p3 = *(const float2*)&h2[k3.x * 2];
        const float w0 = __uint_as_float(k0.y), w1 = __uint_as_float(k1.y);
        const float w2 = __uint_as_float(k2.y), w3 = __uint_as_float(k3.y);
        a0 += p0.x * w0 + p1.x * w1 + p2.x * w2 + p3.x * w3;
        a1 += p0.y * w0 + p1.y * w1 + p2.y * w2 + p3.y * w3;
    }
    for (; i < e; ++i) {
        const uint2 k = csr_pack[i];
        const float2 p = *(const float2*)&h2[k.x * 2];
        const float w = __uint_as_float(k.y);
        a0 += p.x * w;
        a1 += p.y * w;
    }
    out[n * 2 + 0] = a0;
    out[n * 2 + 1] = a1;
}

// ---------------- host ----------------

static inline size_t align_up(size_t x) { return (x + 255) & ~(size_t)255; }

extern "C" void kernel_launch(void* const* d_in, const int* in_sizes, int n_in,
                              void* d_out, int out_size, void* d_ws, size_t ws_size,
                              hipStream_t stream) {
    const float* x   = (const float*)d_in[0];
    const int*   ei  = (const int*)d_in[1];
    const float* W1  = (const float*)d_in[2];
    const float* b1  = (const float*)d_in[3];
    const float* W2  = (const float*)d_in[4];
    const float* b2  = (const float*)d_in[5];
    float* out = (float*)d_out;

    const int* e_src = ei;
    const int* e_dst = ei + N_EDGES;

    char* ws = (char*)d_ws;
    int*   counts   = (int*)ws;             ws += align_up((size_t)N_NODES * 4);
    int*   incl     = (int*)ws;             ws += align_up((size_t)N_NODES * 4);
    int*   bsum     = (int*)ws;             ws += align_up(256 * 4);
    int*   offs     = (int*)ws;             ws += align_up((size_t)(N_NODES + 1) * 4);
    int*   cursor   = (int*)ws;             ws += align_up((size_t)N_NODES * 4);
    float* dinv     = (float*)ws;           ws += align_up((size_t)N_NODES * 4);
    uint2* csr_pack = (uint2*)ws;           ws += align_up((size_t)TOT_E * 8);
    unsigned short* Wt = (unsigned short*)ws; ws += align_up((size_t)HID_C * IN_C * 2);
    unsigned short* h  = (unsigned short*)ws; ws += align_up((size_t)N_NODES * HID_C * 2);
    float* h2       = (float*)ws;           ws += align_up((size_t)N_NODES * 2 * 4);

    const int nb_n = (N_NODES + 255) / 256;   // 196
    const int nb_f = (TOT_E + 1023) / 1024;   // fill: 4 slots/thread

    init0_kernel<<<nb_n, 256, 0, stream>>>(counts, N_NODES);
    prep_kernel<<<PREP_BLOCKS, 256, 0, stream>>>(counts, W1, Wt, e_dst);
    scan1_kernel<<<nb_n, 256, 0, stream>>>(counts, incl, bsum, dinv, N_NODES);
    scan23_kernel<<<nb_n, 256, 0, stream>>>(incl, counts, bsum, offs, cursor,
                                            N_NODES, nb_n);
    fill_kernel<<<nb_f, 256, 0, stream>>>(e_src, e_dst, dinv, cursor, csr_pack);

    gemm_kernel<<<((N_NODES + 127) / 128) * 2, 256, 0, stream>>>(x, Wt, h, N_NODES);

    agg1_kernel<<<N_NODES / 8, 256, 0, stream>>>(h, offs, csr_pack, b1, W2, h2);
    agg2_kernel<<<nb_n, 256, 0, stream>>>(h2, offs, csr_pack, b2, out, N_NODES);
}

// Round 8
// 219.045 us; speedup vs baseline: 1.0306x; 1.0306x over previous
//
#include <hip/hip_runtime.h>
#include <hip/hip_bf16.h>
#include <stdint.h>

#define N_NODES 50000
#define N_EDGES 800000
#define IN_C 512
#define HID_C 256
#define TOT_E (N_EDGES + N_NODES)   // edges + self loops

typedef __attribute__((ext_vector_type(8))) short bf16x8;
typedef __attribute__((ext_vector_type(4))) float f32x4;
typedef __attribute__((address_space(3))) uint32_t lds_u32_t;
typedef __attribute__((address_space(1))) const uint32_t g_u32_t;

__device__ __forceinline__ void g2l16(const void* g, void* l) {
    __builtin_amdgcn_global_load_lds((g_u32_t*)g, (lds_u32_t*)l, 16, 0, 0);
}

__device__ __forceinline__ unsigned short f2bf(float f) {
    uint32_t u = __float_as_uint(f);
    uint32_t r = (u + 0x7fff + ((u >> 16) & 1)) >> 16;
    return (unsigned short)r;
}

// ---------------- init: counts = 0 ----------------

__global__ void init0_kernel(int* counts, int n) {
    int i = blockIdx.x * blockDim.x + threadIdx.x;
    if (i < n) counts[i] = 0;
}

// ---------------- conv: x (f32) -> xb (bf16), pure streaming ----------------
// grid-stride, 2048 blocks x 256 thr, 4 floats/thread/iter

__global__ __launch_bounds__(256) void conv_kernel(const float* __restrict__ x,
                                                   unsigned short* __restrict__ xb) {
    const size_t total4 = (size_t)N_NODES * IN_C / 4;   // float4 count
    const size_t stride = (size_t)gridDim.x * 256;
    for (size_t i = blockIdx.x * 256 + threadIdx.x; i < total4; i += stride) {
        const float4 v = ((const float4*)x)[i];
        uint2 o;
        o.x = (uint32_t)f2bf(v.x) | ((uint32_t)f2bf(v.y) << 16);
        o.y = (uint32_t)f2bf(v.z) | ((uint32_t)f2bf(v.w) << 16);
        ((uint2*)xb)[i] = o;
    }
}

// ---------------- prep: W1 transpose+convert, edge-degree count ----------------

#define TRANSW_BLOCKS 256
#define COUNT_BLOCKS ((N_EDGES + 1023) / 1024)   // 782
#define PREP_BLOCKS (TRANSW_BLOCKS + COUNT_BLOCKS)

__global__ __launch_bounds__(256) void prep_kernel(int* __restrict__ counts,
                                                   const float* __restrict__ W1,
                                                   unsigned short* __restrict__ Wt,
                                                   const int* __restrict__ e_dst) {
    const int b = blockIdx.x;
    const int t = threadIdx.x;
    if (b < TRANSW_BLOCKS) {
        const int n = b;   // 0..255
        for (int k = t; k < IN_C; k += 256)
            Wt[n * IN_C + k] = f2bf(W1[k * HID_C + n]);
    } else {
        const int i0 = ((b - TRANSW_BLOCKS) * 256 + t) * 4;
        if (i0 + 4 <= N_EDGES) {
            const int4 d4 = *(const int4*)&e_dst[i0];
            atomicAdd(&counts[d4.x], 1);
            atomicAdd(&counts[d4.y], 1);
            atomicAdd(&counts[d4.z], 1);
            atomicAdd(&counts[d4.w], 1);
        } else {
            for (int i = i0; i < N_EDGES; ++i) atomicAdd(&counts[e_dst[i]], 1);
        }
    }
}

// ---------------- hierarchical scan over deg = counts+1; emits dinv ----------------

__global__ __launch_bounds__(256) void scan1_kernel(const int* __restrict__ counts,
                                                    int* __restrict__ incl,
                                                    int* __restrict__ bsum,
                                                    float* __restrict__ dinv, int n) {
    __shared__ int buf[256];
    const int i = blockIdx.x * 256 + threadIdx.x;
    const int v = (i < n) ? counts[i] + 1 : 0;    // +1 self loop
    if (i < n) dinv[i] = rsqrtf((float)v);
    buf[threadIdx.x] = v;
    __syncthreads();
    #pragma unroll
    for (int off = 1; off < 256; off <<= 1) {
        const int t2 = (threadIdx.x >= off) ? buf[threadIdx.x - off] : 0;
        __syncthreads();
        buf[threadIdx.x] += t2;
        __syncthreads();
    }
    if (i < n) incl[i] = buf[threadIdx.x];
    if (threadIdx.x == 255) bsum[blockIdx.x] = buf[255];
}

// scan2+scan3 fused: each block reduces bsum[0..bid) itself
__global__ __launch_bounds__(256) void scan23_kernel(const int* __restrict__ incl,
                                                     const int* __restrict__ counts,
                                                     const int* __restrict__ bsum,
                                                     int* __restrict__ offs,
                                                     int* __restrict__ cursor,
                                                     int n, int nb) {
    __shared__ int red[4];
    const int t = threadIdx.x;
    int v = (t < nb && t < blockIdx.x) ? bsum[t] : 0;
    #pragma unroll
    for (int o = 32; o > 0; o >>= 1) v += __shfl_down(v, o, 64);
    const int wid = t >> 6, lane = t & 63;
    if (lane == 0) red[wid] = v;
    __syncthreads();
    const int prefix = red[0] + red[1] + red[2] + red[3];
    const int i = blockIdx.x * 256 + t;
    if (i >= n) return;
    const int e = incl[i] + prefix;
    offs[i + 1] = e;
    cursor[i] = e - (counts[i] + 1);
    if (i == 0) offs[0] = 0;
}

// ---------------- CSR fill: packed {src, norm} uint2, 4 slots/thread ----------------

__global__ __launch_bounds__(256) void fill_kernel(const int* __restrict__ src,
                                                   const int* __restrict__ dst,
                                                   const float* __restrict__ dinv,
                                                   int* cursor,
                                                   uint2* __restrict__ csr_pack) {
    const int i0 = (blockIdx.x * 256 + threadIdx.x) * 4;
    if (i0 >= TOT_E) return;
    int s[4], d[4];
    if (i0 + 4 <= N_EDGES) {
        const int4 s4 = *(const int4*)&src[i0];
        const int4 d4 = *(const int4*)&dst[i0];
        s[0] = s4.x; s[1] = s4.y; s[2] = s4.z; s[3] = s4.w;
        d[0] = d4.x; d[1] = d4.y; d[2] = d4.z; d[3] = d4.w;
    } else {
        #pragma unroll
        for (int j = 0; j < 4; ++j) {
            const int i = i0 + j;
            if (i < N_EDGES)    { s[j] = src[i]; d[j] = dst[i]; }
            else if (i < TOT_E) { s[j] = d[j] = i - N_EDGES; }
            else                { s[j] = d[j] = -1; }
        }
    }
    float ds[4], dd[4];
    #pragma unroll
    for (int j = 0; j < 4; ++j) {
        if (s[j] >= 0) { ds[j] = dinv[s[j]]; dd[j] = dinv[d[j]]; }
    }
    #pragma unroll
    for (int j = 0; j < 4; ++j) {
        if (s[j] >= 0) {
            const int p = atomicAdd(&cursor[d[j]], 1);
            csr_pack[p] = make_uint2((uint32_t)s[j], __float_as_uint(ds[j] * dd[j]));
        }
    }
}

// ---------------- GEMM: h = xb @ W1, m97 structure ----------------
// tile 128x128x64, 256 thr / 4 waves, single-buffer 32KB LDS,
// both operands via global_load_lds w16, XOR-swizzled [row][64] bf16 tiles.

__global__ __launch_bounds__(256) void gemm_kernel(
    const unsigned short* __restrict__ xb,  // [M, 512] bf16
    const unsigned short* __restrict__ Bt,  // [256, 512] bf16 (W1^T)
    unsigned short* __restrict__ hB,        // [M, 256] bf16 out
    int M)
{
    __shared__ unsigned short As[128 * 64];   // 16 KB
    __shared__ unsigned short Bs[128 * 64];   // 16 KB
    const int t = threadIdx.x;
    const int m0 = (blockIdx.x >> 1) * 128;
    const int n0 = (blockIdx.x & 1) * 128;
    const int w = t >> 6, l = t & 63;
    const int wr = (w >> 1) * 64, wc = (w & 1) * 64;
    const int l15 = l & 15, l4 = l >> 4;

    f32x4 acc[4][4] = {};

    auto stage = [&](int kt) {
        #pragma unroll
        for (int q = 0; q < 4; ++q) {
            const int idx = q * 256 + t;
            const int row = idx >> 3;
            const int ck  = (idx & 7) ^ (row & 7);
            int gr = m0 + row; if (gr >= M) gr = M - 1;
            g2l16(&xb[(size_t)gr * IN_C + kt * 64 + ck * 8], &As[idx * 8]);
        }
        #pragma unroll
        for (int q = 0; q < 4; ++q) {
            const int idx = q * 256 + t;
            const int row = idx >> 3;
            const int ck  = (idx & 7) ^ (row & 7);
            g2l16(&Bt[(size_t)(n0 + row) * IN_C + kt * 64 + ck * 8], &Bs[idx * 8]);
        }
    };

    stage(0);
    for (int kt = 0; kt < 8; ++kt) {
        __syncthreads();
        #pragma unroll
        for (int kc = 0; kc < 2; ++kc) {
            bf16x8 a[4], b[4];
            #pragma unroll
            for (int mi = 0; mi < 4; ++mi) {
                const int r  = wr + mi * 16 + l15;
                const int ck = (kc * 4 + l4) ^ (r & 7);
                a[mi] = *(const bf16x8*)&As[r * 64 + ck * 8];
            }
            #pragma unroll
            for (int nj = 0; nj < 4; ++nj) {
                const int r  = wc + nj * 16 + l15;
                const int ck = (kc * 4 + l4) ^ (r & 7);
                b[nj] = *(const bf16x8*)&Bs[r * 64 + ck * 8];
            }
            #pragma unroll
            for (int mi = 0; mi < 4; ++mi)
                #pragma unroll
                for (int nj = 0; nj < 4; ++nj)
                    acc[mi][nj] = __builtin_amdgcn_mfma_f32_16x16x32_bf16(
                        a[mi], b[nj], acc[mi][nj], 0, 0, 0);
        }
        if (kt < 7) {
            __syncthreads();
            stage(kt + 1);
        }
    }

    #pragma unroll
    for (int mi = 0; mi < 4; ++mi)
        #pragma unroll
        for (int nj = 0; nj < 4; ++nj)
            #pragma unroll
            for (int rr = 0; rr < 4; ++rr) {
                const int m = m0 + wr + mi * 16 + l4 * 4 + rr;
                const int n = n0 + wc + nj * 16 + l15;
                if (m < M) hB[(size_t)m * HID_C + n] = f2bf(acc[mi][nj][rr]);
            }
}

// ---------------- fused aggregation-1 + bias + ReLU + @W2 ----------------
// 32-lane group per node (2 nodes/wave): 8 feats/lane via uint4, 4-way gather ILP.

__device__ __forceinline__ void fma8(float* acc, uint4 r, float w) {
    acc[0] += __uint_as_float((r.x & 0xffffu) << 16) * w;
    acc[1] += __uint_as_float(r.x & 0xffff0000u) * w;
    acc[2] += __uint_as_float((r.y & 0xffffu) << 16) * w;
    acc[3] += __uint_as_float(r.y & 0xffff0000u) * w;
    acc[4] += __uint_as_float((r.z & 0xffffu) << 16) * w;
    acc[5] += __uint_as_float(r.z & 0xffff0000u) * w;
    acc[6] += __uint_as_float((r.w & 0xffffu) << 16) * w;
    acc[7] += __uint_as_float(r.w & 0xffff0000u) * w;
}

__global__ __launch_bounds__(256) void agg1_kernel(const unsigned short* __restrict__ h, // [N,256] bf16
                                                   const int* __restrict__ offs,
                                                   const uint2* __restrict__ csr_pack,
                                                   const float* __restrict__ b1,
                                                   const float* __restrict__ W2,  // [256,2]
                                                   float* __restrict__ h2) {      // [N,2]
    const int node = blockIdx.x * 8 + (threadIdx.x >> 5);
    const int g = threadIdx.x & 31;
    const int f0 = g << 3;
    const int s = offs[node], e = offs[node + 1];

    float acc[8] = {};

    for (int base = s; base < e; base += 32) {
        const int rem = e - base;
        const int cnt = rem < 32 ? rem : 32;
        int idx = 0; float nw = 0.f;
        if (g < cnt) {
            const uint2 pk = csr_pack[base + g];
            idx = (int)pk.x; nw = __uint_as_float(pk.y);
        }
        int i = 0;
        for (; i + 4 <= cnt; i += 4) {
            const int   i0 = __shfl(idx, i,     32); const float w0 = __shfl(nw, i,     32);
            const int   i1 = __shfl(idx, i + 1, 32); const float w1 = __shfl(nw, i + 1, 32);
            const int   i2 = __shfl(idx, i + 2, 32); const float w2 = __shfl(nw, i + 2, 32);
            const int   i3 = __shfl(idx, i + 3, 32); const float w3 = __shfl(nw, i + 3, 32);
            const uint4 r0 = *(const uint4*)&h[(size_t)i0 * HID_C + f0];
            const uint4 r1 = *(const uint4*)&h[(size_t)i1 * HID_C + f0];
            const uint4 r2 = *(const uint4*)&h[(size_t)i2 * HID_C + f0];
            const uint4 r3 = *(const uint4*)&h[(size_t)i3 * HID_C + f0];
            fma8(acc, r0, w0); fma8(acc, r1, w1); fma8(acc, r2, w2); fma8(acc, r3, w3);
        }
        for (; i < cnt; ++i) {
            const int   ii = __shfl(idx, i, 32);
            const float w  = __shfl(nw,  i, 32);
            const uint4 r  = *(const uint4*)&h[(size_t)ii * HID_C + f0];
            fma8(acc, r, w);
        }
    }

    const float4 ba = *(const float4*)&b1[f0];
    const float4 bb = *(const float4*)&b1[f0 + 4];
    float v[8];
    v[0] = fmaxf(acc[0] + ba.x, 0.f); v[1] = fmaxf(acc[1] + ba.y, 0.f);
    v[2] = fmaxf(acc[2] + ba.z, 0.f); v[3] = fmaxf(acc[3] + ba.w, 0.f);
    v[4] = fmaxf(acc[4] + bb.x, 0.f); v[5] = fmaxf(acc[5] + bb.y, 0.f);
    v[6] = fmaxf(acc[6] + bb.z, 0.f); v[7] = fmaxf(acc[7] + bb.w, 0.f);

    float c0 = 0.f, c1 = 0.f;
    #pragma unroll
    for (int q = 0; q < 4; ++q) {
        const float4 wv = *(const float4*)&W2[f0 * 2 + q * 4];  // rows f0+2q, f0+2q+1
        c0 += v[2*q] * wv.x + v[2*q+1] * wv.z;
        c1 += v[2*q] * wv.y + v[2*q+1] * wv.w;
    }
    #pragma unroll
    for (int o = 16; o > 0; o >>= 1) {
        c0 += __shfl_down(c0, o, 32);
        c1 += __shfl_down(c1, o, 32);
    }
    if (g == 0) *(float2*)&h2[node * 2] = make_float2(c0, c1);
}

// ---------------- aggregation-2 (+b2), 4-way ILP, packed csr ----------------

__global__ void agg2_kernel(const float* __restrict__ h2,
                            const int* __restrict__ offs,
                            const uint2* __restrict__ csr_pack,
                            const float* __restrict__ b2,
                            float* __restrict__ out, int n_nodes) {
    int n = blockIdx.x * blockDim.x + threadIdx.x;
    if (n >= n_nodes) return;
    const int s = offs[n], e = offs[n + 1];
    float a0 = b2[0], a1 = b2[1];
    int i = s;
    for (; i + 4 <= e; i += 4) {
        const uint2 k0 = csr_pack[i],     k1 = csr_pack[i + 1];
        const uint2 k2 = csr_pack[i + 2], k3 = csr_pack[i + 3];
        const float2 p0 = *(const float2*)&h2[k0.x * 2];
        const float2 p1 = *(const float2*)&h2[k1.x * 2];
        const float2 p2 = *(const float2*)&h2[k2.x * 2];
        const float2 p3 = *(const float2*)&h2[k3.x * 2];
        const float w0 = __uint_as_float(k0.y), w1 = __uint_as_float(k1.y);
        const float w2 = __uint_as_float(k2.y), w3 = __uint_as_float(k3.y);
        a0 += p0.x * w0 + p1.x * w1 + p2.x * w2 + p3.x * w3;
        a1 += p0.y * w0 + p1.y * w1 + p2.y * w2 + p3.y * w3;
    }
    for (; i < e; ++i) {
        const uint2 k = csr_pack[i];
        const float2 p = *(const float2*)&h2[k.x * 2];
        const float w = __uint_as_float(k.y);
        a0 += p.x * w;
        a1 += p.y * w;
    }
    out[n * 2 + 0] = a0;
    out[n * 2 + 1] = a1;
}

// ---------------- host ----------------

static inline size_t align_up(size_t x) { return (x + 255) & ~(size_t)255; }

extern "C" void kernel_launch(void* const* d_in, const int* in_sizes, int n_in,
                              void* d_out, int out_size, void* d_ws, size_t ws_size,
                              hipStream_t stream) {
    const float* x   = (const float*)d_in[0];
    const int*   ei  = (const int*)d_in[1];
    const float* W1  = (const float*)d_in[2];
    const float* b1  = (const float*)d_in[3];
    const float* W2  = (const float*)d_in[4];
    const float* b2  = (const float*)d_in[5];
    float* out = (float*)d_out;

    const int* e_src = ei;
    const int* e_dst = ei + N_EDGES;

    char* ws = (char*)d_ws;
    int*   counts   = (int*)ws;             ws += align_up((size_t)N_NODES * 4);
    int*   incl     = (int*)ws;             ws += align_up((size_t)N_NODES * 4);
    int*   bsum     = (int*)ws;             ws += align_up(256 * 4);
    int*   offs     = (int*)ws;             ws += align_up((size_t)(N_NODES + 1) * 4);
    int*   cursor   = (int*)ws;             ws += align_up((size_t)N_NODES * 4);
    float* dinv     = (float*)ws;           ws += align_up((size_t)N_NODES * 4);
    uint2* csr_pack = (uint2*)ws;           ws += align_up((size_t)TOT_E * 8);
    unsigned short* Wt = (unsigned short*)ws; ws += align_up((size_t)HID_C * IN_C * 2);
    unsigned short* xb = (unsigned short*)ws; ws += align_up((size_t)N_NODES * IN_C * 2);
    unsigned short* h  = (unsigned short*)ws; ws += align_up((size_t)N_NODES * HID_C * 2);
    float* h2       = (float*)ws;           ws += align_up((size_t)N_NODES * 2 * 4);

    const int nb_n = (N_NODES + 255) / 256;   // 196
    const int nb_f = (TOT_E + 1023) / 1024;   // fill: 4 slots/thread

    init0_kernel<<<nb_n, 256, 0, stream>>>(counts, N_NODES);
    prep_kernel<<<PREP_BLOCKS, 256, 0, stream>>>(counts, W1, Wt, e_dst);
    conv_kernel<<<2048, 256, 0, stream>>>(x, xb);
    scan1_kernel<<<nb_n, 256, 0, stream>>>(counts, incl, bsum, dinv, N_NODES);
    scan23_kernel<<<nb_n, 256, 0, stream>>>(incl, counts, bsum, offs, cursor,
                                            N_NODES, nb_n);
    fill_kernel<<<nb_f, 256, 0, stream>>>(e_src, e_dst, dinv, cursor, csr_pack);

    gemm_kernel<<<((N_NODES + 127) / 128) * 2, 256, 0, stream>>>(xb, Wt, h, N_NODES);

    agg1_kernel<<<N_NODES / 8, 256, 0, stream>>>(h, offs, csr_pack, b1, W2, h2);
    agg2_kernel<<<nb_n, 256, 0, stream>>>(h2, offs, csr_pack, b2, out, N_NODES);
}

// Round 9
// 201.281 us; speedup vs baseline: 1.1216x; 1.0883x over previous
//
#include <hip/hip_runtime.h>
#include <hip/hip_bf16.h>
#include <stdint.h>

#define N_NODES 50000
#define N_EDGES 800000
#define IN_C 512
#define HID_C 256
#define TOT_E (N_EDGES + N_NODES)   // edges + self loops

typedef __attribute__((ext_vector_type(8))) short bf16x8;
typedef __attribute__((ext_vector_type(4))) float f32x4;
typedef __attribute__((address_space(3))) uint32_t lds_u32_t;
typedef __attribute__((address_space(1))) const uint32_t g_u32_t;

__device__ __forceinline__ void g2l16(const void* g, void* l) {
    __builtin_amdgcn_global_load_lds((g_u32_t*)g, (lds_u32_t*)l, 16, 0, 0);
}

__device__ __forceinline__ unsigned short f2bf(float f) {
    uint32_t u = __float_as_uint(f);
    uint32_t r = (u + 0x7fff + ((u >> 16) & 1)) >> 16;
    return (unsigned short)r;
}

// ---------------- init: counts = 0 ----------------

__global__ void init0_kernel(int* counts, int n) {
    int i = blockIdx.x * blockDim.x + threadIdx.x;
    if (i < n) counts[i] = 0;
}

// ---- prep2: fused edge-degree count (first), W1 transpose, x->bf16 conv ----
// count blocks first so the latency-bound atomics overlap conv's BW streaming.

#define COUNT_BLOCKS ((N_EDGES + 1023) / 1024)         // 782, 4 edges/thread
#define TRANSW_BLOCKS 256
#define CONV_ROLE_BLOCKS 2048
#define PREP2_BLOCKS (COUNT_BLOCKS + TRANSW_BLOCKS + CONV_ROLE_BLOCKS)

__global__ __launch_bounds__(256) void prep2_kernel(const float* __restrict__ x,
                                                    unsigned short* __restrict__ xb,
                                                    int* __restrict__ counts,
                                                    const float* __restrict__ W1,
                                                    unsigned short* __restrict__ Wt,
                                                    const int* __restrict__ e_dst) {
    const int b = blockIdx.x;
    const int t = threadIdx.x;
    if (b < COUNT_BLOCKS) {
        const int i0 = (b * 256 + t) * 4;
        if (i0 + 4 <= N_EDGES) {
            const int4 d4 = *(const int4*)&e_dst[i0];
            atomicAdd(&counts[d4.x], 1);
            atomicAdd(&counts[d4.y], 1);
            atomicAdd(&counts[d4.z], 1);
            atomicAdd(&counts[d4.w], 1);
        } else {
            for (int i = i0; i < N_EDGES; ++i) atomicAdd(&counts[e_dst[i]], 1);
        }
    } else if (b < COUNT_BLOCKS + TRANSW_BLOCKS) {
        const int n = b - COUNT_BLOCKS;   // 0..255
        for (int k = t; k < IN_C; k += 256)
            Wt[n * IN_C + k] = f2bf(W1[k * HID_C + n]);
    } else {
        const size_t total4 = (size_t)N_NODES * IN_C / 4;
        const size_t stride = (size_t)CONV_ROLE_BLOCKS * 256;
        for (size_t i = (size_t)(b - COUNT_BLOCKS - TRANSW_BLOCKS) * 256 + t;
             i < total4; i += stride) {
            const float4 v = ((const float4*)x)[i];
            uint2 o;
            o.x = (uint32_t)f2bf(v.x) | ((uint32_t)f2bf(v.y) << 16);
            o.y = (uint32_t)f2bf(v.z) | ((uint32_t)f2bf(v.w) << 16);
            ((uint2*)xb)[i] = o;
        }
    }
}

// ---------------- hierarchical scan over deg = counts+1; emits dinv ----------------

__global__ __launch_bounds__(256) void scan1_kernel(const int* __restrict__ counts,
                                                    int* __restrict__ incl,
                                                    int* __restrict__ bsum,
                                                    float* __restrict__ dinv, int n) {
    __shared__ int buf[256];
    const int i = blockIdx.x * 256 + threadIdx.x;
    const int v = (i < n) ? counts[i] + 1 : 0;    // +1 self loop
    if (i < n) dinv[i] = rsqrtf((float)v);
    buf[threadIdx.x] = v;
    __syncthreads();
    #pragma unroll
    for (int off = 1; off < 256; off <<= 1) {
        const int t2 = (threadIdx.x >= off) ? buf[threadIdx.x - off] : 0;
        __syncthreads();
        buf[threadIdx.x] += t2;
        __syncthreads();
    }
    if (i < n) incl[i] = buf[threadIdx.x];
    if (threadIdx.x == 255) bsum[blockIdx.x] = buf[255];
}

// scan2+scan3 fused
__global__ __launch_bounds__(256) void scan23_kernel(const int* __restrict__ incl,
                                                     const int* __restrict__ counts,
                                                     const int* __restrict__ bsum,
                                                     int* __restrict__ offs,
                                                     int* __restrict__ cursor,
                                                     int n, int nb) {
    __shared__ int red[4];
    const int t = threadIdx.x;
    int v = (t < nb && t < blockIdx.x) ? bsum[t] : 0;
    #pragma unroll
    for (int o = 32; o > 0; o >>= 1) v += __shfl_down(v, o, 64);
    const int wid = t >> 6, lane = t & 63;
    if (lane == 0) red[wid] = v;
    __syncthreads();
    const int prefix = red[0] + red[1] + red[2] + red[3];
    const int i = blockIdx.x * 256 + t;
    if (i >= n) return;
    const int e = incl[i] + prefix;
    offs[i + 1] = e;
    cursor[i] = e - (counts[i] + 1);
    if (i == 0) offs[0] = 0;
}

// ---------------- fused GEMM + CSR-fill dispatch ----------------
// blocks [0, GEMM_BLOCKS): gemm tile 128x256x64, 512 thr / 8 waves (wave 64x64)
// blocks [GEMM_BLOCKS, ...): fill role, 2 edges/thread, atomics-then-stores
// fill's atomic/scatter latency hides under gemm's MFMA+staging occupancy.

#define GEMM_BLOCKS ((N_NODES + 127) / 128)            // 391
#define FILL_BLOCKS ((TOT_E + 1023) / 1024)            // 831 (512 thr * 2 edges)
#define GF_BLOCKS (GEMM_BLOCKS + FILL_BLOCKS)

__global__ __launch_bounds__(512) void gf_kernel(
    const unsigned short* __restrict__ xb,  // [M, 512] bf16
    const unsigned short* __restrict__ Bt,  // [256, 512] bf16 (W1^T)
    unsigned short* __restrict__ hB,        // [M, 256] bf16 out
    int M,
    const int* __restrict__ src,
    const int* __restrict__ dst,
    const float* __restrict__ dinv,
    int* cursor,
    uint2* __restrict__ csr_pack)
{
    __shared__ unsigned short As[128 * 64];   // 16 KB
    __shared__ unsigned short Bs[256 * 64];   // 32 KB
    const int t = threadIdx.x;

    if (blockIdx.x >= GEMM_BLOCKS) {
        // ---------- fill role ----------
        const int i0 = ((blockIdx.x - GEMM_BLOCKS) * 512 + t) * 2;
        if (i0 >= TOT_E) return;
        int s0, d0, s1, d1;
        if (i0 + 2 <= N_EDGES) {
            const int2 s2 = *(const int2*)&src[i0];
            const int2 d2 = *(const int2*)&dst[i0];
            s0 = s2.x; s1 = s2.y; d0 = d2.x; d1 = d2.y;
        } else {
            // tail: element-wise (covers edge/self-loop boundary)
            int sv[2], dv[2];
            #pragma unroll
            for (int j = 0; j < 2; ++j) {
                const int i = i0 + j;
                if (i < N_EDGES)    { sv[j] = src[i]; dv[j] = dst[i]; }
                else if (i < TOT_E) { sv[j] = dv[j] = i - N_EDGES; }
                else                { sv[j] = dv[j] = -1; }
            }
            s0 = sv[0]; d0 = dv[0]; s1 = sv[1]; d1 = dv[1];
        }
        float n0 = 0.f, n1 = 0.f;
        if (s0 >= 0) n0 = dinv[s0] * dinv[d0];
        if (s1 >= 0) n1 = dinv[s1] * dinv[d1];
        int p0 = -1, p1 = -1;
        if (s0 >= 0) p0 = atomicAdd(&cursor[d0], 1);
        if (s1 >= 0) p1 = atomicAdd(&cursor[d1], 1);
        if (p0 >= 0) csr_pack[p0] = make_uint2((uint32_t)s0, __float_as_uint(n0));
        if (p1 >= 0) csr_pack[p1] = make_uint2((uint32_t)s1, __float_as_uint(n1));
        return;
    }

    // ---------- gemm role ----------
    const int m0 = blockIdx.x * 128;
    const int w = t >> 6, l = t & 63;
    const int wr = (w >> 2) * 64;          // 0 / 64
    const int wc = (w & 3) * 64;           // 0 / 64 / 128 / 192
    const int l15 = l & 15, l4 = l >> 4;

    f32x4 acc[4][4] = {};

    auto stage = [&](int kt) {
        #pragma unroll
        for (int q = 0; q < 2; ++q) {       // A: 1024 slots / 512 thr
            const int idx = q * 512 + t;
            const int row = idx >> 3;
            const int ck  = (idx & 7) ^ (row & 7);
            int gr = m0 + row; if (gr >= M) gr = M - 1;
            g2l16(&xb[(size_t)gr * IN_C + kt * 64 + ck * 8], &As[idx * 8]);
        }
        #pragma unroll
        for (int q = 0; q < 4; ++q) {       // B: 2048 slots / 512 thr
            const int idx = q * 512 + t;
            const int row = idx >> 3;
            const int ck  = (idx & 7) ^ (row & 7);
            g2l16(&Bt[(size_t)row * IN_C + kt * 64 + ck * 8], &Bs[idx * 8]);
        }
    };

    stage(0);
    for (int kt = 0; kt < 8; ++kt) {
        __syncthreads();
        #pragma unroll
        for (int kc = 0; kc < 2; ++kc) {
            bf16x8 a[4], b[4];
            #pragma unroll
            for (int mi = 0; mi < 4; ++mi) {
                const int r  = wr + mi * 16 + l15;
                const int ck = (kc * 4 + l4) ^ (r & 7);
                a[mi] = *(const bf16x8*)&As[r * 64 + ck * 8];
            }
            #pragma unroll
            for (int nj = 0; nj < 4; ++nj) {
                const int r  = wc + nj * 16 + l15;
                const int ck = (kc * 4 + l4) ^ (r & 7);
                b[nj] = *(const bf16x8*)&Bs[r * 64 + ck * 8];
            }
            #pragma unroll
            for (int mi = 0; mi < 4; ++mi)
                #pragma unroll
                for (int nj = 0; nj < 4; ++nj)
                    acc[mi][nj] = __builtin_amdgcn_mfma_f32_16x16x32_bf16(
                        a[mi], b[nj], acc[mi][nj], 0, 0, 0);
        }
        if (kt < 7) {
            __syncthreads();
            stage(kt + 1);
        }
    }

    #pragma unroll
    for (int mi = 0; mi < 4; ++mi)
        #pragma unroll
        for (int nj = 0; nj < 4; ++nj)
            #pragma unroll
            for (int rr = 0; rr < 4; ++rr) {
                const int m = m0 + wr + mi * 16 + l4 * 4 + rr;
                const int n = wc + nj * 16 + l15;
                if (m < M) hB[(size_t)m * HID_C + n] = f2bf(acc[mi][nj][rr]);
            }
}

// ---------------- fused aggregation-1 + bias + ReLU + @W2 ----------------
// 32-lane group per node (2 nodes/wave): 8 feats/lane via uint4, 4-way gather ILP.

__device__ __forceinline__ void fma8(float* acc, uint4 r, float w) {
    acc[0] += __uint_as_float((r.x & 0xffffu) << 16) * w;
    acc[1] += __uint_as_float(r.x & 0xffff0000u) * w;
    acc[2] += __uint_as_float((r.y & 0xffffu) << 16) * w;
    acc[3] += __uint_as_float(r.y & 0xffff0000u) * w;
    acc[4] += __uint_as_float((r.z & 0xffffu) << 16) * w;
    acc[5] += __uint_as_float(r.z & 0xffff0000u) * w;
    acc[6] += __uint_as_float((r.w & 0xffffu) << 16) * w;
    acc[7] += __uint_as_float(r.w & 0xffff0000u) * w;
}

__global__ __launch_bounds__(256) void agg1_kernel(const unsigned short* __restrict__ h, // [N,256] bf16
                                                   const int* __restrict__ offs,
                                                   const uint2* __restrict__ csr_pack,
                                                   const float* __restrict__ b1,
                                                   const float* __restrict__ W2,  // [256,2]
                                                   float* __restrict__ h2) {      // [N,2]
    const int node = blockIdx.x * 8 + (threadIdx.x >> 5);
    const int g = threadIdx.x & 31;
    const int f0 = g << 3;
    const int s = offs[node], e = offs[node + 1];

    float acc[8] = {};

    for (int base = s; base < e; base += 32) {
        const int rem = e - base;
        const int cnt = rem < 32 ? rem : 32;
        int idx = 0; float nw = 0.f;
        if (g < cnt) {
            const uint2 pk = csr_pack[base + g];
            idx = (int)pk.x; nw = __uint_as_float(pk.y);
        }
        int i = 0;
        for (; i + 4 <= cnt; i += 4) {
            const int   i0 = __shfl(idx, i,     32); const float w0 = __shfl(nw, i,     32);
            const int   i1 = __shfl(idx, i + 1, 32); const float w1 = __shfl(nw, i + 1, 32);
            const int   i2 = __shfl(idx, i + 2, 32); const float w2 = __shfl(nw, i + 2, 32);
            const int   i3 = __shfl(idx, i + 3, 32); const float w3 = __shfl(nw, i + 3, 32);
            const uint4 r0 = *(const uint4*)&h[(size_t)i0 * HID_C + f0];
            const uint4 r1 = *(const uint4*)&h[(size_t)i1 * HID_C + f0];
            const uint4 r2 = *(const uint4*)&h[(size_t)i2 * HID_C + f0];
            const uint4 r3 = *(const uint4*)&h[(size_t)i3 * HID_C + f0];
            fma8(acc, r0, w0); fma8(acc, r1, w1); fma8(acc, r2, w2); fma8(acc, r3, w3);
        }
        for (; i < cnt; ++i) {
            const int   ii = __shfl(idx, i, 32);
            const float w  = __shfl(nw,  i, 32);
            const uint4 r  = *(const uint4*)&h[(size_t)ii * HID_C + f0];
            fma8(acc, r, w);
        }
    }

    const float4 ba = *(const float4*)&b1[f0];
    const float4 bb = *(const float4*)&b1[f0 + 4];
    float v[8];
    v[0] = fmaxf(acc[0] + ba.x, 0.f); v[1] = fmaxf(acc[1] + ba.y, 0.f);
    v[2] = fmaxf(acc[2] + ba.z, 0.f); v[3] = fmaxf(acc[3] + ba.w, 0.f);
    v[4] = fmaxf(acc[4] + bb.x, 0.f); v[5] = fmaxf(acc[5] + bb.y, 0.f);
    v[6] = fmaxf(acc[6] + bb.z, 0.f); v[7] = fmaxf(acc[7] + bb.w, 0.f);

    float c0 = 0.f, c1 = 0.f;
    #pragma unroll
    for (int q = 0; q < 4; ++q) {
        const float4 wv = *(const float4*)&W2[f0 * 2 + q * 4];  // rows f0+2q, f0+2q+1
        c0 += v[2*q] * wv.x + v[2*q+1] * wv.z;
        c1 += v[2*q] * wv.y + v[2*q+1] * wv.w;
    }
    #pragma unroll
    for (int o = 16; o > 0; o >>= 1) {
        c0 += __shfl_down(c0, o, 32);
        c1 += __shfl_down(c1, o, 32);
    }
    if (g == 0) *(float2*)&h2[node * 2] = make_float2(c0, c1);
}

// ---------------- aggregation-2 (+b2), 4-way ILP, packed csr ----------------

__global__ void agg2_kernel(const float* __restrict__ h2,
                            const int* __restrict__ offs,
                            const uint2* __restrict__ csr_pack,
                            const float* __restrict__ b2,
                            float* __restrict__ out, int n_nodes) {
    int n = blockIdx.x * blockDim.x + threadIdx.x;
    if (n >= n_nodes) return;
    const int s = offs[n], e = offs[n + 1];
    float a0 = b2[0], a1 = b2[1];
    int i = s;
    for (; i + 4 <= e; i += 4) {
        const uint2 k0 = csr_pack[i],     k1 = csr_pack[i + 1];
        const uint2 k2 = csr_pack[i + 2], k3 = csr_pack[i + 3];
        const float2 p0 = *(const float2*)&h2[k0.x * 2];
        const float2 p1 = *(const float2*)&h2[k1.x * 2];
        const float2 p2 = *(const float2*)&h2[k2.x * 2];
        const float2 p3 = *(const float2*)&h2[k3.x * 2];
        const float w0 = __uint_as_float(k0.y), w1 = __uint_as_float(k1.y);
        const float w2 = __uint_as_float(k2.y), w3 = __uint_as_float(k3.y);
        a0 += p0.x * w0 + p1.x * w1 + p2.x * w2 + p3.x * w3;
        a1 += p0.y * w0 + p1.y * w1 + p2.y * w2 + p3.y * w3;
    }
    for (; i < e; ++i) {
        const uint2 k = csr_pack[i];
        const float2 p = *(const float2*)&h2[k.x * 2];
        const float w = __uint_as_float(k.y);
        a0 += p.x * w;
        a1 += p.y * w;
    }
    out[n * 2 + 0] = a0;
    out[n * 2 + 1] = a1;
}

// ---------------- host ----------------

static inline size_t align_up(size_t x) { return (x + 255) & ~(size_t)255; }

extern "C" void kernel_launch(void* const* d_in, const int* in_sizes, int n_in,
                              void* d_out, int out_size, void* d_ws, size_t ws_size,
                              hipStream_t stream) {
    const float* x   = (const float*)d_in[0];
    const int*   ei  = (const int*)d_in[1];
    const float* W1  = (const float*)d_in[2];
    const float* b1  = (const float*)d_in[3];
    const float* W2  = (const float*)d_in[4];
    const float* b2  = (const float*)d_in[5];
    float* out = (float*)d_out;

    const int* e_src = ei;
    const int* e_dst = ei + N_EDGES;

    char* ws = (char*)d_ws;
    int*   counts   = (int*)ws;             ws += align_up((size_t)N_NODES * 4);
    int*   incl     = (int*)ws;             ws += align_up((size_t)N_NODES * 4);
    int*   bsum     = (int*)ws;             ws += align_up(256 * 4);
    int*   offs     = (int*)ws;             ws += align_up((size_t)(N_NODES + 1) * 4);
    int*   cursor   = (int*)ws;             ws += align_up((size_t)N_NODES * 4);
    float* dinv     = (float*)ws;           ws += align_up((size_t)N_NODES * 4);
    uint2* csr_pack = (uint2*)ws;           ws += align_up((size_t)TOT_E * 8);
    unsigned short* Wt = (unsigned short*)ws; ws += align_up((size_t)HID_C * IN_C * 2);
    unsigned short* xb = (unsigned short*)ws; ws += align_up((size_t)N_NODES * IN_C * 2);
    unsigned short* h  = (unsigned short*)ws; ws += align_up((size_t)N_NODES * HID_C * 2);
    float* h2       = (float*)ws;           ws += align_up((size_t)N_NODES * 2 * 4);

    const int nb_n = (N_NODES + 255) / 256;   // 196

    init0_kernel<<<nb_n, 256, 0, stream>>>(counts, N_NODES);
    prep2_kernel<<<PREP2_BLOCKS, 256, 0, stream>>>(x, xb, counts, W1, Wt, e_dst);
    scan1_kernel<<<nb_n, 256, 0, stream>>>(counts, incl, bsum, dinv, N_NODES);
    scan23_kernel<<<nb_n, 256, 0, stream>>>(incl, counts, bsum, offs, cursor,
                                            N_NODES, nb_n);
    gf_kernel<<<GF_BLOCKS, 512, 0, stream>>>(xb, Wt, h, N_NODES,
                                             e_src, e_dst, dinv, cursor, csr_pack);

    agg1_kernel<<<N_NODES / 8, 256, 0, stream>>>(h, offs, csr_pack, b1, W2, h2);
    agg2_kernel<<<nb_n, 256, 0, stream>>>(h2, offs, csr_pack, b2, out, N_NODES);
}

// Round 10
// 195.979 us; speedup vs baseline: 1.1519x; 1.0271x over previous
//
#include <hip/hip_runtime.h>
#include <hip/hip_bf16.h>
#include <stdint.h>

#define N_NODES 50000
#define N_EDGES 800000
#define IN_C 512
#define HID_C 256
#define TOT_E (N_EDGES + N_NODES)   // edges + self loops

typedef __attribute__((ext_vector_type(8))) short bf16x8;
typedef __attribute__((ext_vector_type(4))) float f32x4;
typedef __attribute__((address_space(3))) uint32_t lds_u32_t;
typedef __attribute__((address_space(1))) const uint32_t g_u32_t;

__device__ __forceinline__ void g2l16(const void* g, void* l) {
    __builtin_amdgcn_global_load_lds((g_u32_t*)g, (lds_u32_t*)l, 16, 0, 0);
}

__device__ __forceinline__ unsigned short f2bf(float f) {
    uint32_t u = __float_as_uint(f);
    uint32_t r = (u + 0x7fff + ((u >> 16) & 1)) >> 16;
    return (unsigned short)r;
}

// ---------------- init: counts = 0 ----------------

__global__ void init0_kernel(int* counts, int n) {
    int i = blockIdx.x * blockDim.x + threadIdx.x;
    if (i < n) counts[i] = 0;
}

// ---------------- conv: x (f32) -> xb (bf16), pure streaming (standalone) ----------------

__global__ __launch_bounds__(256) void conv_kernel(const float* __restrict__ x,
                                                   unsigned short* __restrict__ xb) {
    const size_t total4 = (size_t)N_NODES * IN_C / 4;   // float4 count
    const size_t stride = (size_t)gridDim.x * 256;
    for (size_t i = blockIdx.x * 256 + threadIdx.x; i < total4; i += stride) {
        const float4 v = ((const float4*)x)[i];
        uint2 o;
        o.x = (uint32_t)f2bf(v.x) | ((uint32_t)f2bf(v.y) << 16);
        o.y = (uint32_t)f2bf(v.z) | ((uint32_t)f2bf(v.w) << 16);
        ((uint2*)xb)[i] = o;
    }
}

// ---------------- count: edge dst degree histogram (standalone) ----------------

#define COUNT_BLOCKS ((N_EDGES + 1023) / 1024)   // 782, 4 edges/thread

__global__ __launch_bounds__(256) void count_kernel(int* __restrict__ counts,
                                                    const int* __restrict__ e_dst) {
    const int i0 = (blockIdx.x * 256 + threadIdx.x) * 4;
    if (i0 + 4 <= N_EDGES) {
        const int4 d4 = *(const int4*)&e_dst[i0];
        atomicAdd(&counts[d4.x], 1);
        atomicAdd(&counts[d4.y], 1);
        atomicAdd(&counts[d4.z], 1);
        atomicAdd(&counts[d4.w], 1);
    } else {
        for (int i = i0; i < N_EDGES; ++i) atomicAdd(&counts[e_dst[i]], 1);
    }
}

// ------- scan1 + transw roles: blocks [0,196) scan deg=counts+1, emit dinv;
// ------- blocks [196, 196+256): W1 transpose+convert (needed only by gf later)

#define SCAN_BLOCKS ((N_NODES + 255) / 256)   // 196

__global__ __launch_bounds__(256) void scan1t_kernel(const int* __restrict__ counts,
                                                     int* __restrict__ incl,
                                                     int* __restrict__ bsum,
                                                     float* __restrict__ dinv,
                                                     const float* __restrict__ W1,
                                                     unsigned short* __restrict__ Wt,
                                                     int n) {
    const int t = threadIdx.x;
    if (blockIdx.x >= SCAN_BLOCKS) {
        const int c = blockIdx.x - SCAN_BLOCKS;   // 0..255
        for (int k = t; k < IN_C; k += 256)
            Wt[c * IN_C + k] = f2bf(W1[k * HID_C + c]);
        return;
    }
    __shared__ int buf[256];
    const int i = blockIdx.x * 256 + t;
    const int v = (i < n) ? counts[i] + 1 : 0;    // +1 self loop
    if (i < n) dinv[i] = rsqrtf((float)v);
    buf[t] = v;
    __syncthreads();
    #pragma unroll
    for (int off = 1; off < 256; off <<= 1) {
        const int t2 = (t >= off) ? buf[t - off] : 0;
        __syncthreads();
        buf[t] += t2;
        __syncthreads();
    }
    if (i < n) incl[i] = buf[t];
    if (t == 255) bsum[blockIdx.x] = buf[255];
}

// scan2+scan3 fused
__global__ __launch_bounds__(256) void scan23_kernel(const int* __restrict__ incl,
                                                     const int* __restrict__ counts,
                                                     const int* __restrict__ bsum,
                                                     int* __restrict__ offs,
                                                     int* __restrict__ cursor,
                                                     int n, int nb) {
    __shared__ int red[4];
    const int t = threadIdx.x;
    int v = (t < nb && t < blockIdx.x) ? bsum[t] : 0;
    #pragma unroll
    for (int o = 32; o > 0; o >>= 1) v += __shfl_down(v, o, 64);
    const int wid = t >> 6, lane = t & 63;
    if (lane == 0) red[wid] = v;
    __syncthreads();
    const int prefix = red[0] + red[1] + red[2] + red[3];
    const int i = blockIdx.x * 256 + t;
    if (i >= n) return;
    const int e = incl[i] + prefix;
    offs[i + 1] = e;
    cursor[i] = e - (counts[i] + 1);
    if (i == 0) offs[0] = 0;
}

// ---------------- fused GEMM + CSR-fill dispatch (unchanged from R9) ----------------

#define GEMM_BLOCKS ((N_NODES + 127) / 128)            // 391
#define FILL_BLOCKS ((TOT_E + 1023) / 1024)            // 831 (512 thr * 2 edges)
#define GF_BLOCKS (GEMM_BLOCKS + FILL_BLOCKS)

__global__ __launch_bounds__(512) void gf_kernel(
    const unsigned short* __restrict__ xb,  // [M, 512] bf16
    const unsigned short* __restrict__ Bt,  // [256, 512] bf16 (W1^T)
    unsigned short* __restrict__ hB,        // [M, 256] bf16 out
    int M,
    const int* __restrict__ src,
    const int* __restrict__ dst,
    const float* __restrict__ dinv,
    int* cursor,
    uint2* __restrict__ csr_pack)
{
    __shared__ unsigned short As[128 * 64];   // 16 KB
    __shared__ unsigned short Bs[256 * 64];   // 32 KB
    const int t = threadIdx.x;

    if (blockIdx.x >= GEMM_BLOCKS) {
        // ---------- fill role ----------
        const int i0 = ((blockIdx.x - GEMM_BLOCKS) * 512 + t) * 2;
        if (i0 >= TOT_E) return;
        int s0, d0, s1, d1;
        if (i0 + 2 <= N_EDGES) {
            const int2 s2 = *(const int2*)&src[i0];
            const int2 d2 = *(const int2*)&dst[i0];
            s0 = s2.x; s1 = s2.y; d0 = d2.x; d1 = d2.y;
        } else {
            int sv[2], dv[2];
            #pragma unroll
            for (int j = 0; j < 2; ++j) {
                const int i = i0 + j;
                if (i < N_EDGES)    { sv[j] = src[i]; dv[j] = dst[i]; }
                else if (i < TOT_E) { sv[j] = dv[j] = i - N_EDGES; }
                else                { sv[j] = dv[j] = -1; }
            }
            s0 = sv[0]; d0 = dv[0]; s1 = sv[1]; d1 = dv[1];
        }
        float n0 = 0.f, n1 = 0.f;
        if (s0 >= 0) n0 = dinv[s0] * dinv[d0];
        if (s1 >= 0) n1 = dinv[s1] * dinv[d1];
        int p0 = -1, p1 = -1;
        if (s0 >= 0) p0 = atomicAdd(&cursor[d0], 1);
        if (s1 >= 0) p1 = atomicAdd(&cursor[d1], 1);
        if (p0 >= 0) csr_pack[p0] = make_uint2((uint32_t)s0, __float_as_uint(n0));
        if (p1 >= 0) csr_pack[p1] = make_uint2((uint32_t)s1, __float_as_uint(n1));
        return;
    }

    // ---------- gemm role ----------
    const int m0 = blockIdx.x * 128;
    const int w = t >> 6, l = t & 63;
    const int wr = (w >> 2) * 64;          // 0 / 64
    const int wc = (w & 3) * 64;           // 0 / 64 / 128 / 192
    const int l15 = l & 15, l4 = l >> 4;

    f32x4 acc[4][4] = {};

    auto stage = [&](int kt) {
        #pragma unroll
        for (int q = 0; q < 2; ++q) {       // A: 1024 slots / 512 thr
            const int idx = q * 512 + t;
            const int row = idx >> 3;
            const int ck  = (idx & 7) ^ (row & 7);
            int gr = m0 + row; if (gr >= M) gr = M - 1;
            g2l16(&xb[(size_t)gr * IN_C + kt * 64 + ck * 8], &As[idx * 8]);
        }
        #pragma unroll
        for (int q = 0; q < 4; ++q) {       // B: 2048 slots / 512 thr
            const int idx = q * 512 + t;
            const int row = idx >> 3;
            const int ck  = (idx & 7) ^ (row & 7);
            g2l16(&Bt[(size_t)row * IN_C + kt * 64 + ck * 8], &Bs[idx * 8]);
        }
    };

    stage(0);
    for (int kt = 0; kt < 8; ++kt) {
        __syncthreads();
        #pragma unroll
        for (int kc = 0; kc < 2; ++kc) {
            bf16x8 a[4], b[4];
            #pragma unroll
            for (int mi = 0; mi < 4; ++mi) {
                const int r  = wr + mi * 16 + l15;
                const int ck = (kc * 4 + l4) ^ (r & 7);
                a[mi] = *(const bf16x8*)&As[r * 64 + ck * 8];
            }
            #pragma unroll
            for (int nj = 0; nj < 4; ++nj) {
                const int r  = wc + nj * 16 + l15;
                const int ck = (kc * 4 + l4) ^ (r & 7);
                b[nj] = *(const bf16x8*)&Bs[r * 64 + ck * 8];
            }
            #pragma unroll
            for (int mi = 0; mi < 4; ++mi)
                #pragma unroll
                for (int nj = 0; nj < 4; ++nj)
                    acc[mi][nj] = __builtin_amdgcn_mfma_f32_16x16x32_bf16(
                        a[mi], b[nj], acc[mi][nj], 0, 0, 0);
        }
        if (kt < 7) {
            __syncthreads();
            stage(kt + 1);
        }
    }

    #pragma unroll
    for (int mi = 0; mi < 4; ++mi)
        #pragma unroll
        for (int nj = 0; nj < 4; ++nj)
            #pragma unroll
            for (int rr = 0; rr < 4; ++rr) {
                const int m = m0 + wr + mi * 16 + l4 * 4 + rr;
                const int n = wc + nj * 16 + l15;
                if (m < M) hB[(size_t)m * HID_C + n] = f2bf(acc[mi][nj][rr]);
            }
}

// ---------------- fused aggregation-1 + bias + ReLU + @W2 ----------------

__device__ __forceinline__ void fma8(float* acc, uint4 r, float w) {
    acc[0] += __uint_as_float((r.x & 0xffffu) << 16) * w;
    acc[1] += __uint_as_float(r.x & 0xffff0000u) * w;
    acc[2] += __uint_as_float((r.y & 0xffffu) << 16) * w;
    acc[3] += __uint_as_float(r.y & 0xffff0000u) * w;
    acc[4] += __uint_as_float((r.z & 0xffffu) << 16) * w;
    acc[5] += __uint_as_float(r.z & 0xffff0000u) * w;
    acc[6] += __uint_as_float((r.w & 0xffffu) << 16) * w;
    acc[7] += __uint_as_float(r.w & 0xffff0000u) * w;
}

__global__ __launch_bounds__(256) void agg1_kernel(const unsigned short* __restrict__ h, // [N,256] bf16
                                                   const int* __restrict__ offs,
                                                   const uint2* __restrict__ csr_pack,
                                                   const float* __restrict__ b1,
                                                   const float* __restrict__ W2,  // [256,2]
                                                   float* __restrict__ h2) {      // [N,2]
    const int node = blockIdx.x * 8 + (threadIdx.x >> 5);
    const int g = threadIdx.x & 31;
    const int f0 = g << 3;
    const int s = offs[node], e = offs[node + 1];

    float acc[8] = {};

    for (int base = s; base < e; base += 32) {
        const int rem = e - base;
        const int cnt = rem < 32 ? rem : 32;
        int idx = 0; float nw = 0.f;
        if (g < cnt) {
            const uint2 pk = csr_pack[base + g];
            idx = (int)pk.x; nw = __uint_as_float(pk.y);
        }
        int i = 0;
        for (; i + 4 <= cnt; i += 4) {
            const int   i0 = __shfl(idx, i,     32); const float w0 = __shfl(nw, i,     32);
            const int   i1 = __shfl(idx, i + 1, 32); const float w1 = __shfl(nw, i + 1, 32);
            const int   i2 = __shfl(idx, i + 2, 32); const float w2 = __shfl(nw, i + 2, 32);
            const int   i3 = __shfl(idx, i + 3, 32); const float w3 = __shfl(nw, i + 3, 32);
            const uint4 r0 = *(const uint4*)&h[(size_t)i0 * HID_C + f0];
            const uint4 r1 = *(const uint4*)&h[(size_t)i1 * HID_C + f0];
            const uint4 r2 = *(const uint4*)&h[(size_t)i2 * HID_C + f0];
            const uint4 r3 = *(const uint4*)&h[(size_t)i3 * HID_C + f0];
            fma8(acc, r0, w0); fma8(acc, r1, w1); fma8(acc, r2, w2); fma8(acc, r3, w3);
        }
        for (; i < cnt; ++i) {
            const int   ii = __shfl(idx, i, 32);
            const float w  = __shfl(nw,  i, 32);
            const uint4 r  = *(const uint4*)&h[(size_t)ii * HID_C + f0];
            fma8(acc, r, w);
        }
    }

    const float4 ba = *(const float4*)&b1[f0];
    const float4 bb = *(const float4*)&b1[f0 + 4];
    float v[8];
    v[0] = fmaxf(acc[0] + ba.x, 0.f); v[1] = fmaxf(acc[1] + ba.y, 0.f);
    v[2] = fmaxf(acc[2] + ba.z, 0.f); v[3] = fmaxf(acc[3] + ba.w, 0.f);
    v[4] = fmaxf(acc[4] + bb.x, 0.f); v[5] = fmaxf(acc[5] + bb.y, 0.f);
    v[6] = fmaxf(acc[6] + bb.z, 0.f); v[7] = fmaxf(acc[7] + bb.w, 0.f);

    float c0 = 0.f, c1 = 0.f;
    #pragma unroll
    for (int q = 0; q < 4; ++q) {
        const float4 wv = *(const float4*)&W2[f0 * 2 + q * 4];  // rows f0+2q, f0+2q+1
        c0 += v[2*q] * wv.x + v[2*q+1] * wv.z;
        c1 += v[2*q] * wv.y + v[2*q+1] * wv.w;
    }
    #pragma unroll
    for (int o = 16; o > 0; o >>= 1) {
        c0 += __shfl_down(c0, o, 32);
        c1 += __shfl_down(c1, o, 32);
    }
    if (g == 0) *(float2*)&h2[node * 2] = make_float2(c0, c1);
}

// ---------------- aggregation-2 (+b2), 4-way ILP, packed csr ----------------

__global__ void agg2_kernel(const float* __restrict__ h2,
                            const int* __restrict__ offs,
                            const uint2* __restrict__ csr_pack,
                            const float* __restrict__ b2,
                            float* __restrict__ out, int n_nodes) {
    int n = blockIdx.x * blockDim.x + threadIdx.x;
    if (n >= n_nodes) return;
    const int s = offs[n], e = offs[n + 1];
    float a0 = b2[0], a1 = b2[1];
    int i = s;
    for (; i + 4 <= e; i += 4) {
        const uint2 k0 = csr_pack[i],     k1 = csr_pack[i + 1];
        const uint2 k2 = csr_pack[i + 2], k3 = csr_pack[i + 3];
        const float2 p0 = *(const float2*)&h2[k0.x * 2];
        const float2 p1 = *(const float2*)&h2[k1.x * 2];
        const float2 p2 = *(const float2*)&h2[k2.x * 2];
        const float2 p3 = *(const float2*)&h2[k3.x * 2];
        const float w0 = __uint_as_float(k0.y), w1 = __uint_as_float(k1.y);
        const float w2 = __uint_as_float(k2.y), w3 = __uint_as_float(k3.y);
        a0 += p0.x * w0 + p1.x * w1 + p2.x * w2 + p3.x * w3;
        a1 += p0.y * w0 + p1.y * w1 + p2.y * w2 + p3.y * w3;
    }
    for (; i < e; ++i) {
        const uint2 k = csr_pack[i];
        const float2 p = *(const float2*)&h2[k.x * 2];
        const float w = __uint_as_float(k.y);
        a0 += p.x * w;
        a1 += p.y * w;
    }
    out[n * 2 + 0] = a0;
    out[n * 2 + 1] = a1;
}

// ---------------- host ----------------

static inline size_t align_up(size_t x) { return (x + 255) & ~(size_t)255; }

extern "C" void kernel_launch(void* const* d_in, const int* in_sizes, int n_in,
                              void* d_out, int out_size, void* d_ws, size_t ws_size,
                              hipStream_t stream) {
    const float* x   = (const float*)d_in[0];
    const int*   ei  = (const int*)d_in[1];
    const float* W1  = (const float*)d_in[2];
    const float* b1  = (const float*)d_in[3];
    const float* W2  = (const float*)d_in[4];
    const float* b2  = (const float*)d_in[5];
    float* out = (float*)d_out;

    const int* e_src = ei;
    const int* e_dst = ei + N_EDGES;

    char* ws = (char*)d_ws;
    int*   counts   = (int*)ws;             ws += align_up((size_t)N_NODES * 4);
    int*   incl     = (int*)ws;             ws += align_up((size_t)N_NODES * 4);
    int*   bsum     = (int*)ws;             ws += align_up(256 * 4);
    int*   offs     = (int*)ws;             ws += align_up((size_t)(N_NODES + 1) * 4);
    int*   cursor   = (int*)ws;             ws += align_up((size_t)N_NODES * 4);
    float* dinv     = (float*)ws;           ws += align_up((size_t)N_NODES * 4);
    uint2* csr_pack = (uint2*)ws;           ws += align_up((size_t)TOT_E * 8);
    unsigned short* Wt = (unsigned short*)ws; ws += align_up((size_t)HID_C * IN_C * 2);
    unsigned short* xb = (unsigned short*)ws; ws += align_up((size_t)N_NODES * IN_C * 2);
    unsigned short* h  = (unsigned short*)ws; ws += align_up((size_t)N_NODES * HID_C * 2);
    float* h2       = (float*)ws;           ws += align_up((size_t)N_NODES * 2 * 4);

    const int nb_n = (N_NODES + 255) / 256;   // 196

    init0_kernel<<<nb_n, 256, 0, stream>>>(counts, N_NODES);
    conv_kernel<<<2048, 256, 0, stream>>>(x, xb);
    count_kernel<<<COUNT_BLOCKS, 256, 0, stream>>>(counts, e_dst);
    scan1t_kernel<<<SCAN_BLOCKS + 256, 256, 0, stream>>>(counts, incl, bsum, dinv,
                                                         W1, Wt, N_NODES);
    scan23_kernel<<<nb_n, 256, 0, stream>>>(incl, counts, bsum, offs, cursor,
                                            N_NODES, nb_n);
    gf_kernel<<<GF_BLOCKS, 512, 0, stream>>>(xb, Wt, h, N_NODES,
                                             e_src, e_dst, dinv, cursor, csr_pack);

    agg1_kernel<<<N_NODES / 8, 256, 0, stream>>>(h, offs, csr_pack, b1, W2, h2);
    agg2_kernel<<<nb_n, 256, 0, stream>>>(h2, offs, csr_pack, b2, out, N_NODES);
}